// Round 2
// baseline (513.581 us; speedup 1.0000x reference)
//
#include <hip/hip_runtime.h>

// LeakageNlinCore: out[pos,:] = M(W) · f(x[pos,:])
//   f[c]    = (xr^2+xi^2)*xr,  f[64+c] = (xr^2+xi^2)*xi
//   M row k=2c+o: W[c,o,:126] scattered over columns j!=c (real half) /
//   64+j!=64+c (imag half); diagonal 2x2 blocks are zero.
//
// Design (round 1 == round 0 resubmit; round 0 hit GPUAcquisitionTimeout):
//   - 128 threads/block, thread k owns M row k in 128 VGPRs (loaded once per
//     block from W with the LOO index expansion; L2-resident, ~13% overhead).
//   - Each block handles P=16 positions: stage f into LDS (coalesced float2
//     x loads + nonlinearity), then per position 32 broadcast ds_read_b128
//     + 128 v_fmac_f32 split over 4 accumulator chains; coalesced 512B store.

#define NPOS 32768      // B*S = 4*8192
#define P    16         // positions per block
#define NBLK (NPOS / P) // 2048 blocks

__global__ __launch_bounds__(128, 3)
void leakage_nlin_kernel(const float* __restrict__ x,
                         const float* __restrict__ W,
                         float* __restrict__ out) {
    __shared__ float f_lds[P][128];

    const int k = threadIdx.x;   // output row 0..127, k = 2*c + o
    const int c = k >> 1;

    // ---- Load & expand this thread's M row into registers -----------------
    // W[c][o][n] is flat W[k*126 + n]. Column j<64 (real): n = j - (j>c);
    // column 64+j (imag): n = 63 + j - (j>c); column j==c (both halves) = 0.
    const float* __restrict__ Wrow = W + k * 126;
    float m[128];
#pragma unroll
    for (int j = 0; j < 64; ++j) {
        const bool skip = (j == c);
        const int  idx  = j - (j > c ? 1 : 0);        // 0..62
        const int  i1   = skip ? 0 : idx;             // safe speculative idx
        const int  i2   = skip ? 0 : (63 + idx);      // 63..125
        const float v1  = Wrow[i1];
        const float v2  = Wrow[i2];
        m[j]      = skip ? 0.0f : v1;
        m[64 + j] = skip ? 0.0f : v2;
    }

    // ---- Stage f for this block's P positions into LDS --------------------
    const int p0 = blockIdx.x * P;                    // first position
    const float2* __restrict__ x2 = (const float2*)(x + (size_t)p0 * 128);
    // P*64 = 1024 (pos,channel) pairs, 128 threads -> 8 pairs each
#pragma unroll
    for (int it = 0; it < 8; ++it) {
        const int q  = k + it * 128;                  // pair index
        const int p  = q >> 6;
        const int cc = q & 63;
        const float2 v = x2[q];                       // (xr, xi), coalesced 8B
        const float amp = v.x * v.x + v.y * v.y;
        f_lds[p][cc]      = amp * v.x;
        f_lds[p][64 + cc] = amp * v.y;
    }
    __syncthreads();

    // ---- Matvec: each thread computes out[p][k] for all P positions -------
    float* __restrict__ outp = out + (size_t)p0 * 128 + k;
#pragma unroll 2
    for (int p = 0; p < P; ++p) {
        const float4* __restrict__ f4 = (const float4*)f_lds[p];
        float a0 = 0.0f, a1 = 0.0f, a2 = 0.0f, a3 = 0.0f;
#pragma unroll
        for (int jv = 0; jv < 32; ++jv) {
            const float4 f = f4[jv];                  // broadcast ds_read_b128
            a0 = fmaf(m[4 * jv + 0], f.x, a0);
            a1 = fmaf(m[4 * jv + 1], f.y, a1);
            a2 = fmaf(m[4 * jv + 2], f.z, a2);
            a3 = fmaf(m[4 * jv + 3], f.w, a3);
        }
        outp[(size_t)p * 128] = (a0 + a1) + (a2 + a3); // coalesced 512B/block
    }
}

extern "C" void kernel_launch(void* const* d_in, const int* in_sizes, int n_in,
                              void* d_out, int out_size, void* d_ws, size_t ws_size,
                              hipStream_t stream) {
    const float* x = (const float*)d_in[0];   // [4,8192,64,2] fp32
    const float* W = (const float*)d_in[1];   // [64,2,126]    fp32
    float* out = (float*)d_out;               // [4,8192,64,2] fp32

    hipLaunchKernelGGL(leakage_nlin_kernel,
                       dim3(NBLK), dim3(128), 0, stream,
                       x, W, out);
}

// Round 4
// 74.407 us; speedup vs baseline: 6.9023x; 6.9023x over previous
//
#include <hip/hip_runtime.h>

// LeakageNlinCore as fused GEMM: out[pos,:] = M(W) · f(x[pos,:]),
//   f[k] = k<64 ? amp_k*xr_k : amp_{k-64}*xi_{k-64},  amp = xr^2+xi^2
//   M row n (=2c+o): W[c,o,:126] scattered over cols != c (2x2 zero diag).
//
// Round 4: SINGLE kernel (round-3 post-mortem: expand->main dependency via
// d_ws was correct on the first launch but deterministically wrong on every
// post-timing launch — d_ws is re-poisoned around timed launches; remove all
// cross-kernel state). All W expansion + x staging done per block in LDS with
// fully coalesced global reads (round 3's 512B-strided per-lane x loads also
// suspected of the 88.9us vs ~8us predicted).

typedef _Float16 f16x8 __attribute__((ext_vector_type(8)));
typedef _Float16 f16x2 __attribute__((ext_vector_type(2)));
typedef float    floatx4 __attribute__((ext_vector_type(4)));

#define NPOS 32768              // B*S
#define PT   4                  // 16-position MFMA tiles per block
#define TILE (16 * PT)          // 64 positions per block
#define NBLK (NPOS / TILE)      // 512 blocks
#define MS   136                // padded LDS row stride in f16 (136*2B = 272B,
                                // 68 dwords ≡ 4 mod 32 → balanced banks, 16B-aligned)

__global__ __launch_bounds__(256, 2)
void leakage_kernel(const float* __restrict__ x,
                    const float* __restrict__ W,
                    float* __restrict__ out) {
    __shared__ __align__(16) _Float16 Mt[128][MS];   // M (f16): [row n][col k]
    __shared__ __align__(16) _Float16 fsh[TILE][MS]; // f (f16): [pos][k]

    const int tid  = threadIdx.x;
    const int w    = tid >> 6;       // wave 0..3 -> n-tiles {2w, 2w+1}
    const int lane = tid & 63;
    const int q    = lane >> 4, r = lane & 15;

    // ---- Build M table from W: coalesced flat float4 read (16128 floats) ---
    // W flat index F = n*126 + m. m<63: real weight for channel ch=m+(m>=c);
    // m>=63: imag weight for ch=(m-63)+((m-63)>=c); c = n>>1. Col k = ch or 64+ch.
#pragma unroll
    for (int it = 0; it < 16; ++it) {
        const int g = tid + 256 * it;            // float4 index, < 4032
        if (g < 4032) {
            const float4 v = ((const float4*)W)[g];
#pragma unroll
            for (int u = 0; u < 4; ++u) {
                const int F  = 4 * g + u;
                const int n  = F / 126;          // magic-mul, compiler const div
                const int m  = F - 126 * n;
                const int c  = n >> 1;
                const int mh = (m < 63) ? m : (m - 63);
                const int ch = mh + (mh >= c ? 1 : 0);
                const int k  = (m < 63) ? ch : (64 + ch);
                const float val = (u == 0) ? v.x : (u == 1) ? v.y
                                : (u == 2) ? v.z : v.w;
                Mt[n][k] = (_Float16)val;
            }
        }
    }
    // Zero the excluded-channel (diagonal) entries; disjoint from above writes.
    if (tid < 128) {
        const int c = tid >> 1;
        Mt[tid][c]      = (_Float16)0.f;
        Mt[tid][64 + c] = (_Float16)0.f;
    }

    // ---- Stage f for this block's TILE positions: coalesced x float4 read --
    const int pbase = blockIdx.x * TILE;
    const float4* __restrict__ x4 = (const float4*)x + (size_t)pbase * 32;
#pragma unroll
    for (int it = 0; it < 2 * PT; ++it) {
        const int g = tid + 256 * it;            // float4 index in block region
        const int p = g >> 5;                    // local position 0..TILE-1
        const int i = g & 31;                    // channel pair (2i, 2i+1)
        const float4 v = x4[g];                  // (xr0, xi0, xr1, xi1)
        const float a0 = v.x * v.x + v.y * v.y;
        const float a1 = v.z * v.z + v.w * v.w;
        f16x2 fr = { (_Float16)(a0 * v.x), (_Float16)(a1 * v.z) };
        f16x2 fi = { (_Float16)(a0 * v.y), (_Float16)(a1 * v.w) };
        *(f16x2*)&fsh[p][2 * i]      = fr;       // f[2i], f[2i+1]
        *(f16x2*)&fsh[p][64 + 2 * i] = fi;       // f[64+2i], f[64+2i+1]
    }
    __syncthreads();

    // ---- B fragments for this wave's two 16-wide n-tiles (32 VGPRs) -------
    // B frag t holds B[k=32t+8q+j][n=nt*16+r] = M[n][k]; contiguous 8 f16.
    const int nt0 = 2 * w, nt1 = 2 * w + 1;
    f16x8 B0[4], B1[4];
#pragma unroll
    for (int t = 0; t < 4; ++t) {
        B0[t] = *(const f16x8*)&Mt[nt0 * 16 + r][32 * t + 8 * q];
        B1[t] = *(const f16x8*)&Mt[nt1 * 16 + r][32 * t + 8 * q];
    }

    // ---- Main: per 16-position tile, 4 A ds_read_b128 + 8 MFMAs + stores --
#pragma unroll
    for (int pt = 0; pt < PT; ++pt) {
        const int pr = pt * 16 + r;              // A operand: m = lane&15 = pos
        f16x8 A0 = *(const f16x8*)&fsh[pr][      8 * q];  // k =  8q..8q+7
        f16x8 A1 = *(const f16x8*)&fsh[pr][32 +  8 * q];  // k = 32+..
        f16x8 A2 = *(const f16x8*)&fsh[pr][64 +  8 * q];  // k = 64+..
        f16x8 A3 = *(const f16x8*)&fsh[pr][96 +  8 * q];  // k = 96+..

        floatx4 C0 = {0.f, 0.f, 0.f, 0.f};
        floatx4 C1 = {0.f, 0.f, 0.f, 0.f};
        C0 = __builtin_amdgcn_mfma_f32_16x16x32_f16(A0, B0[0], C0, 0, 0, 0);
        C1 = __builtin_amdgcn_mfma_f32_16x16x32_f16(A0, B1[0], C1, 0, 0, 0);
        C0 = __builtin_amdgcn_mfma_f32_16x16x32_f16(A1, B0[1], C0, 0, 0, 0);
        C1 = __builtin_amdgcn_mfma_f32_16x16x32_f16(A1, B1[1], C1, 0, 0, 0);
        C0 = __builtin_amdgcn_mfma_f32_16x16x32_f16(A2, B0[2], C0, 0, 0, 0);
        C1 = __builtin_amdgcn_mfma_f32_16x16x32_f16(A2, B1[2], C1, 0, 0, 0);
        C0 = __builtin_amdgcn_mfma_f32_16x16x32_f16(A3, B0[3], C0, 0, 0, 0);
        C1 = __builtin_amdgcn_mfma_f32_16x16x32_f16(A3, B1[3], C1, 0, 0, 0);

        // C layout (16x16): col = lane&15 = r (n), row = q*4+reg (m = pos).
        float* __restrict__ op = out + (size_t)(pbase + pt * 16) * 128;
#pragma unroll
        for (int reg = 0; reg < 4; ++reg) {
            const int m = q * 4 + reg;
            op[(size_t)m * 128 + nt0 * 16 + r] = C0[reg];
            op[(size_t)m * 128 + nt1 * 16 + r] = C1[reg];
        }
    }
}

extern "C" void kernel_launch(void* const* d_in, const int* in_sizes, int n_in,
                              void* d_out, int out_size, void* d_ws, size_t ws_size,
                              hipStream_t stream) {
    const float* x = (const float*)d_in[0];   // [4,8192,64,2] fp32
    const float* W = (const float*)d_in[1];   // [64,2,126]    fp32
    float* out = (float*)d_out;               // [4,8192,64,2] fp32

    hipLaunchKernelGGL(leakage_kernel, dim3(NBLK), dim3(256), 0, stream,
                       x, W, out);
}

// Round 5
// 72.203 us; speedup vs baseline: 7.1130x; 1.0305x over previous
//
#include <hip/hip_runtime.h>

// LeakageNlinCore as fused GEMM: out[pos,:] = M(W) · f(x[pos,:]),
//   f[k] = k<64 ? amp_k*xr_k : amp_{k-64}*xi_{k-64},  amp = xr^2+xi^2
//   M row n (=2c+o): W[c,o,:126] scattered over cols != c (2x2 zero diag).
//
// Round 5 (round-4 post-mortem: kernel itself <45us — outranked by 45us
// harness fills in top-5 — so dur_us ~74 carries a ~50us harness floor;
// remaining kernel excess over the ~10us model attributed to 512 redundant
// per-block M-builds at ~850 VALU + 64 ds_write_b16 per thread):
//   - 256 blocks x 512 threads x 128 positions (2 chunks of 64): half the
//     M-builds, each 2x more parallel.
//   - Division-free build indexing: e = n*64 + m2 (shift/mask), coalesced
//     float2 W loads, 2 scatter writes per element pair. ~2.5x fewer VALU,
//     2x fewer DS ops in the build.
//   - MFMA main loop unchanged in spirit: wave w owns n-tile w; per 16-pos
//     tile 4 ds_read_b128 (A) + 4 MFMA + 4 direct 64B-segment stores.

typedef _Float16 f16x8 __attribute__((ext_vector_type(8)));
typedef _Float16 f16x2 __attribute__((ext_vector_type(2)));
typedef float    floatx4 __attribute__((ext_vector_type(4)));

#define NPOS  32768             // B*S
#define CPOS  64                // positions per chunk
#define NCH   2                 // chunks per block
#define BPOS  (CPOS * NCH)      // 128 positions per block
#define NBLK  (NPOS / BPOS)     // 256 blocks
#define NTHR  512               // 8 waves
#define MS    136               // padded LDS row stride in f16 (272B; 68 dw
                                // = 4 mod 32 -> balanced banks, 16B aligned)

__global__ __launch_bounds__(NTHR, 2)
void leakage_kernel(const float* __restrict__ x,
                    const float* __restrict__ W,
                    float* __restrict__ out) {
    __shared__ __align__(16) _Float16 Mt[128][MS];   // M (f16): [row n][col k]
    __shared__ __align__(16) _Float16 fsh[CPOS][MS]; // f (f16): [pos][k]

    const int tid  = threadIdx.x;
    const int w    = tid >> 6;        // wave 0..7 -> n-tile w
    const int lane = tid & 63;
    const int q    = lane >> 4, r = lane & 15;

    // ---- Build M from W: division-free, coalesced float2 reads ------------
    // e = n*64 + m2 (m2 = float2 index within row, 63 valid + 1 pad slot).
    // Element m = 2*m2+u: half = (m>=63); mh = m - 63*half;
    // ch = mh + (mh>=c); col k = 64*half + ch; c = n>>1.
    const float2* __restrict__ W2 = (const float2*)W;
#pragma unroll
    for (int it = 0; it < 16; ++it) {
        const int e  = tid + NTHR * it;      // < 8192
        const int n  = e >> 6;
        const int m2 = e & 63;
        if (m2 < 63) {
            const int c = n >> 1;
            const float2 v = W2[n * 63 + m2];
#pragma unroll
            for (int u = 0; u < 2; ++u) {
                const int m    = 2 * m2 + u;
                const int half = (m >= 63) ? 1 : 0;
                const int mh   = m - 63 * half;
                const int k    = 64 * half + mh + (mh >= c ? 1 : 0);
                Mt[n][k] = (_Float16)(u == 0 ? v.x : v.y);
            }
        }
    }
    // Diagonal (excluded-channel) zeros; disjoint from scatter writes.
    if (tid < 128) {
        const int c = tid >> 1;
        Mt[tid][c]      = (_Float16)0.f;
        Mt[tid][64 + c] = (_Float16)0.f;
    }

    const int pblk = blockIdx.x * BPOS;

    // ---- Stage chunk 0 (independent of M build; same barrier covers both) --
    {
        const float4* __restrict__ x4 = (const float4*)x + (size_t)pblk * 32;
#pragma unroll
        for (int it = 0; it < 4; ++it) {
            const int g = tid + NTHR * it;   // float4 idx, < 2048
            const int p = g >> 5;            // local pos 0..63
            const int i = g & 31;            // channel pair (2i, 2i+1)
            const float4 v = x4[g];          // (xr0, xi0, xr1, xi1)
            const float a0 = v.x * v.x + v.y * v.y;
            const float a1 = v.z * v.z + v.w * v.w;
            *(f16x2*)&fsh[p][2 * i] =
                f16x2{ (_Float16)(a0 * v.x), (_Float16)(a1 * v.z) };
            *(f16x2*)&fsh[p][64 + 2 * i] =
                f16x2{ (_Float16)(a0 * v.y), (_Float16)(a1 * v.w) };
        }
    }
    __syncthreads();

    // ---- B fragments: wave w owns n-tile w (cols n = 16w..16w+15) ---------
    // Frag t holds B[k=32t+8q+j][n=16w+r] = M[n][k]; contiguous 8 f16.
    f16x8 B0 = *(const f16x8*)&Mt[16 * w + r][ 0 + 8 * q];
    f16x8 B1 = *(const f16x8*)&Mt[16 * w + r][32 + 8 * q];
    f16x8 B2 = *(const f16x8*)&Mt[16 * w + r][64 + 8 * q];
    f16x8 B3 = *(const f16x8*)&Mt[16 * w + r][96 + 8 * q];

#pragma unroll
    for (int ch = 0; ch < NCH; ++ch) {
        // ---- Compute chunk ch: 4 position-tiles x (4 A-reads + 4 MFMA) ----
#pragma unroll
        for (int pt = 0; pt < 4; ++pt) {
            const int pr = pt * 16 + r;      // A operand: m = lane&15 = pos
            f16x8 A0 = *(const f16x8*)&fsh[pr][ 0 + 8 * q];
            f16x8 A1 = *(const f16x8*)&fsh[pr][32 + 8 * q];
            f16x8 A2 = *(const f16x8*)&fsh[pr][64 + 8 * q];
            f16x8 A3 = *(const f16x8*)&fsh[pr][96 + 8 * q];

            floatx4 C = {0.f, 0.f, 0.f, 0.f};
            C = __builtin_amdgcn_mfma_f32_16x16x32_f16(A0, B0, C, 0, 0, 0);
            C = __builtin_amdgcn_mfma_f32_16x16x32_f16(A1, B1, C, 0, 0, 0);
            C = __builtin_amdgcn_mfma_f32_16x16x32_f16(A2, B2, C, 0, 0, 0);
            C = __builtin_amdgcn_mfma_f32_16x16x32_f16(A3, B3, C, 0, 0, 0);

            // C layout (16x16): col = r (n), row = 4q+reg (m = position).
            float* __restrict__ op =
                out + (size_t)(pblk + ch * CPOS + pt * 16) * 128;
#pragma unroll
            for (int reg = 0; reg < 4; ++reg) {
                op[(size_t)(4 * q + reg) * 128 + 16 * w + r] = C[reg];
            }
        }

        // ---- Stage next chunk (reuses fsh) --------------------------------
        if (ch + 1 < NCH) {
            __syncthreads();   // all waves done reading fsh
            const float4* __restrict__ x4 =
                (const float4*)x + (size_t)(pblk + (ch + 1) * CPOS) * 32;
#pragma unroll
            for (int it = 0; it < 4; ++it) {
                const int g = tid + NTHR * it;
                const int p = g >> 5;
                const int i = g & 31;
                const float4 v = x4[g];
                const float a0 = v.x * v.x + v.y * v.y;
                const float a1 = v.z * v.z + v.w * v.w;
                *(f16x2*)&fsh[p][2 * i] =
                    f16x2{ (_Float16)(a0 * v.x), (_Float16)(a1 * v.z) };
                *(f16x2*)&fsh[p][64 + 2 * i] =
                    f16x2{ (_Float16)(a0 * v.y), (_Float16)(a1 * v.w) };
            }
            __syncthreads();
        }
    }
}

extern "C" void kernel_launch(void* const* d_in, const int* in_sizes, int n_in,
                              void* d_out, int out_size, void* d_ws, size_t ws_size,
                              hipStream_t stream) {
    const float* x = (const float*)d_in[0];   // [4,8192,64,2] fp32
    const float* W = (const float*)d_in[1];   // [64,2,126]    fp32
    float* out = (float*)d_out;               // [4,8192,64,2] fp32

    hipLaunchKernelGGL(leakage_kernel, dim3(NBLK), dim3(NTHR), 0, stream,
                       x, W, out);
}